// Round 1
// 667.838 us; speedup vs baseline: 1.1395x; 1.1395x over previous
//
#include <hip/hip_runtime.h>
#include <math.h>
#include <stdint.h>

typedef unsigned short u16;
typedef unsigned int   u32;
typedef short short8 __attribute__((ext_vector_type(8)));
typedef float v4f    __attribute__((ext_vector_type(4)));

#define DEVI static __device__ __forceinline__

struct __align__(8)  U2 { u32 x, y; };
struct __align__(16) U4 { u32 x, y, z, w; };

static const int BB = 4, LL = 8192;
static const int BL = BB * LL;           // 32768 rows

DEVI float bf2f(u16 u){ u32 v = ((u32)u) << 16; float f; __builtin_memcpy(&f, &v, 4); return f; }
DEVI u16  f2bf(float f){ u32 u; __builtin_memcpy(&u, &f, 4); return (u16)((u + 0x7fffu + ((u >> 16) & 1u)) >> 16); }
DEVI float geluf(float x){ return 0.5f * x * (1.0f + erff(x * 0.7071067811865475f)); }

DEVI void ldsload16(const void* g, void* l){
  __builtin_amdgcn_global_load_lds(
      (const __attribute__((address_space(1))) u32*)(uintptr_t)g,
      (__attribute__((address_space(3)))  u32*)(u32)(uintptr_t)l,
      16, 0, 0);
}

// ---------------- f32 -> bf16 convert, 4 tensors in one launch ----------------
__global__ __launch_bounds__(256) void k_cvt4(
    const float* __restrict__ s0, u16* __restrict__ d0, int n0,
    const float* __restrict__ s1, u16* __restrict__ d1, int n1,
    const float* __restrict__ s2, u16* __restrict__ d2, int n2,
    const float* __restrict__ s3, u16* __restrict__ d3, int n3){
  int i = blockIdx.x * 256 + threadIdx.x;
  if (i < n0){ d0[i] = f2bf(s0[i]); return; }
  i -= n0;
  if (i < n1){ d1[i] = f2bf(s1[i]); return; }
  i -= n1;
  if (i < n2){ d2[i] = f2bf(s2[i]); return; }
  i -= n2;
  if (i < n3){ d3[i] = f2bf(s3[i]); }
}

// ---------------- LayerNorm over 512 (f32 in, bf16 out) ----------------
__global__ __launch_bounds__(256) void k_ln1(const float* __restrict__ x, const float* __restrict__ g,
                                             const float* __restrict__ b, u16* __restrict__ xn){
  int row = blockIdx.x, t = threadIdx.x;
  const float2* xr = (const float2*)(x + (int64_t)row * 512);
  float2 p = xr[t];
  float s = p.x + p.y, ss = p.x * p.x + p.y * p.y;
  for (int off = 32; off; off >>= 1){ s += __shfl_down(s, off); ss += __shfl_down(ss, off); }
  __shared__ float red[8];
  int w = t >> 6, lane = t & 63;
  if (!lane){ red[w] = s; red[4 + w] = ss; }
  __syncthreads();
  s  = red[0] + red[1] + red[2] + red[3];
  ss = red[4] + red[5] + red[6] + red[7];
  float m = s * (1.0f / 512.0f), var = ss * (1.0f / 512.0f) - m * m;
  float rs = rsqrtf(var + 1e-5f);
  float2 gv = ((const float2*)g)[t], bv = ((const float2*)b)[t];
  float r0 = (p.x - m) * rs * gv.x + bv.x;
  float r1 = (p.y - m) * rs * gv.y + bv.y;
  ((u32*)(xn + (int64_t)row * 512))[t] = (u32)f2bf(r0) | ((u32)f2bf(r1) << 16);
}

// ---------------- LayerNorm over 128 (bf16 in, f32 params, bf16 out) ----------------
__global__ __launch_bounds__(256) void k_ln2(const u16* __restrict__ u, const float* __restrict__ g,
                                             const float* __restrict__ b, u16* __restrict__ un){
  int row = blockIdx.x * 4 + (threadIdx.x >> 6);
  int lane = threadIdx.x & 63;
  const u32* ur = (const u32*)(u + (int64_t)row * 128);
  u32 pv = ur[lane];
  float a = bf2f((u16)(pv & 0xffff)), c = bf2f((u16)(pv >> 16));
  float s = a + c, ss = a * a + c * c;
  for (int off = 32; off; off >>= 1){ s += __shfl_xor(s, off); ss += __shfl_xor(ss, off); }
  float m = s * (1.0f / 128.0f), var = ss * (1.0f / 128.0f) - m * m;
  float rs = rsqrtf(var + 1e-5f);
  float2 gv = ((const float2*)g)[lane], bv = ((const float2*)b)[lane];
  float r0 = (a - m) * rs * gv.x + bv.x;
  float r1 = (c - m) * rs * gv.y + bv.y;
  ((u32*)(un + (int64_t)row * 128))[lane] = (u32)f2bf(r0) | ((u32)f2bf(r1) << 16);
}

// ---------------- transpose un[BL,128] -> unT[(b,c,h), i] [8192,512] ----------------
__global__ __launch_bounds__(256) void k_transpose(const u16* __restrict__ un, u16* __restrict__ unT){
  int bc = blockIdx.x >> 3, it = blockIdx.x & 7;
  int b = bc >> 4, cc = bc & 15;
  __shared__ __align__(16) u16 tile[64][128];
  const u16* src = un + ((int64_t)(b * 8192 + cc * 512 + it * 64)) * 128;
  int t = threadIdx.x;
  for (int p = 0; p < 4; p++){
    int id = p * 256 + t; int ri = id >> 4, seg = id & 15;
    *(U4*)&tile[ri][seg * 8] = *(const U4*)(src + (int64_t)ri * 128 + seg * 8);
  }
  __syncthreads();
  u16* dst = unT + ((int64_t)(bc * 128)) * 512 + it * 64;
  for (int p = 0; p < 4; p++){
    int id = p * 256 + t; int h = id >> 3, seg = id & 7;
    U4 pk; u16* pv = (u16*)&pk;
    for (int k2 = 0; k2 < 8; k2++) pv[k2] = tile[seg * 8 + k2][h];
    *(U4*)(dst + (int64_t)h * 512 + seg * 8) = pk;
  }
}

// ---------------- DSS tables (f32 params) ----------------
__global__ __launch_bounds__(512) void k_prep(const float* lam_re, const float* lam_im,
    const float* C_re, const float* C_im,
    u16* ZC, u16* PC, u16* VC, u16* ccat, float* cre, float* cim, float* zT){
  int n = blockIdx.x, t = threadIdx.x;
  float lr = -expf(lam_re[n]);
  float li =  expf(lam_im[n]);
  float mag = expf(lr * (float)t), ph = li * (float)t;
  float er = mag * cosf(ph), ei = mag * sinf(ph);
  ZC[(int64_t)n * 512 + (511 - t)]         = f2bf(er);
  ZC[(int64_t)(512 + n) * 512 + (511 - t)] = f2bf(ei);
  VC[(int64_t)t * 1024 + n]       = f2bf(er);
  VC[(int64_t)t * 1024 + 512 + n] = f2bf(-ei);
  float mag2 = expf(lr * (float)(t + 1)), ph2 = li * (float)(t + 1);
  PC[(int64_t)t * 1024 + n]       = f2bf(mag2 * cosf(ph2));
  PC[(int64_t)t * 1024 + 512 + n] = f2bf(-mag2 * sinf(ph2));
  if (t == 0){
    float m5 = expf(lr * 512.0f), p5 = li * 512.0f;
    zT[n] = m5 * cosf(p5); zT[512 + n] = m5 * sinf(p5);
  }
  if (t < 128){
    float e1m = expf(lr);
    float e1r = e1m * cosf(li), e1i = e1m * sinf(li);
    float nr = e1r - 1.0f, ni = e1i;
    float d2 = lr * lr + li * li;
    float qr = (nr * lr + ni * li) / d2, qi = (ni * lr - nr * li) / d2;
    float Cr = C_re[t * 512 + n], Ci = C_im[t * 512 + n];
    float vr = Cr * qr - Ci * qi, vi = Cr * qi + Ci * qr;
    cre[t * 512 + n] = vr; cim[t * 512 + n] = vi;
    ccat[(int64_t)t * 1024 + n] = f2bf(vr); ccat[(int64_t)t * 1024 + 512 + n] = f2bf(vi);
  }
}

// ---------------- block-Toeplitz build ----------------
__global__ __launch_bounds__(512) void k_rcat(const float* __restrict__ kern, u16* __restrict__ Rcat){
  int h = blockIdx.x >> 7, a = blockIdx.x & 127;
  int kcol = threadIdx.x;
  int d = 3 - (kcol >> 7);
  int delay = d * 128 + a - (kcol & 127);
  float val = (delay >= 0 && delay < 512) ? kern[delay * 128 + h] : 0.0f;
  Rcat[((int64_t)(h * 128 + a)) * 512 + kcol] = f2bf(val);
}

// ---------------- chunk scan + W = c * Scarry ----------------
__global__ __launch_bounds__(256) void k_scan(const float* __restrict__ S, const float* __restrict__ cre,
    const float* __restrict__ cim, const float* __restrict__ zT, u16* __restrict__ WT){
  int tid = blockIdx.x * 256 + threadIdx.x;   // 262144
  int n = tid & 511, bh = tid >> 9, b = bh >> 7, h = bh & 127;
  float cr = cre[h * 512 + n], ci = cim[h * 512 + n];
  float zr = zT[n], zi = zT[512 + n];
  float sR = 0.0f, sI = 0.0f;
  for (int cc = 0; cc < 16; cc++){
    int64_t m = (int64_t)(b * 16 + cc) * 128 + h;
    float wR = cr * sR - ci * sI, wI = cr * sI + ci * sR;
    WT[m * 1024 + n] = f2bf(wR);
    WT[m * 1024 + 512 + n] = f2bf(wI);
    float aR = S[m * 1024 + n], aI = S[m * 1024 + 512 + n];
    float nR = zr * sR - zi * sI + aR;
    sI = zr * sI + zi * sR + aI;
    sR = nR;
  }
}

// ---------------- y = Yloc + Ycross + un*D_skip ----------------
__global__ __launch_bounds__(256) void k_assemble(const float* __restrict__ Yloc, const float* __restrict__ Ycross,
    const u16* __restrict__ un, const float* __restrict__ Dskip, u16* __restrict__ y){
  int64_t e = (int64_t)blockIdx.x * 256 + threadIdx.x;
  int h = (int)(e & 127); int64_t bl = e >> 7;
  int b = (int)(bl >> 13), l = (int)(bl & 8191);
  int cc = l >> 9, ii = l & 511, bc = b * 16 + cc;
  float val = Yloc[((int64_t)h * 512 + ii) * 64 + bc]
            + Ycross[(int64_t)ii * 8192 + (int64_t)bc * 128 + h]
            + bf2f(un[e]) * Dskip[h];
  y[e] = f2bf(val);
}

// ---------------- generic BT GEMM: C[m,n] = sum_k A[m,k]*B[n,k] ----------------
// EPI: 0 = f32 direct store; 1 = gelu->bf16; 2 = *aux1(bf16)->bf16;
//      3 = +auxf1[row,col] + auxf2[col] -> f32 direct store
// TRI: block-Toeplitz mode (A has 128 rows; per row-block ib=by: A base shift
//      (3-ib)*128, K_eff=(ib+1)*128). Yloc local-conv in ONE launch.
template<int EPI, bool TRI = false>
__global__ __launch_bounds__(256) void k_gemm(
    const u16* __restrict__ A, int64_t lda, int64_t aZ,
    const u16* __restrict__ B, int64_t ldb, int64_t bZ,
    void* Cp, int64_t ldc, int64_t cZ,
    int K, int Nvalid,
    const u16* aux1, const float* auxf1, const float* auxf2)
{
  __shared__ union __align__(16) SMU { u16 st[2][4096]; float ep[4][1088]; } sm;
  const int tid = threadIdx.x;
  const int lane = tid & 63, w = tid >> 6;
  const int wr = w >> 1, wc = w & 1, q = lane >> 4, c16 = lane & 15;
  const int sRow = lane >> 2, sSeg = lane & 3;
  const int z = blockIdx.z;

  // XCD-aware swizzle: keep all col-blocks of one row-strip on one XCD,
  // temporally adjacent -> A-strip fetched into exactly one L2.
  int bx = blockIdx.x, by = blockIdx.y;
  if (!TRI && (gridDim.y & 7) == 0 && gridDim.x > 1){
    u32 idx = by * gridDim.x + bx;
    u32 xcd = idx & 7, s = idx >> 3;
    bx = s % gridDim.x;
    by = (s / gridDim.x) * 8 + xcd;
  }
  const int64_t m0 = (int64_t)by * 128;
  const int64_t n0 = (int64_t)bx * 128;

  const u16* Ab = A + (int64_t)z * aZ;
  const u16* Bp = B + (int64_t)z * bZ;
  int Keff = K;
  if (TRI){
    Ab += 384 - m0;              // (3-ib)*128 column shift
    Keff = (int)(m0 + 128);      // (ib+1)*128
  }

  v4f acc[4][4];
  #pragma unroll
  for (int i = 0; i < 4; i++)
    #pragma unroll
    for (int j = 0; j < 4; j++)
      acc[i][j] = (v4f)0.0f;

  for (int k0 = 0; k0 < Keff; k0 += 32){
    #pragma unroll
    for (int half = 0; half < 2; half++){
      int r0 = (half * 4 + w) * 16;
      int64_t arow = (TRI ? (int64_t)0 : m0) + r0 + sRow;
      ldsload16(Ab + arow * lda + k0 + sSeg * 8, &sm.st[0][r0 * 32]);
      int64_t brow = n0 + r0 + sRow;
      if (brow >= Nvalid) brow = Nvalid - 1;
      ldsload16(Bp + brow * ldb + k0 + sSeg * 8, &sm.st[1][r0 * 32]);
    }
    __syncthreads();
    short8 af[4], bfr[4];
    const u16* aB = &sm.st[0][(wr * 64 + c16) * 32 + q * 8];
    const u16* bB = &sm.st[1][(wc * 64 + c16) * 32 + q * 8];
    #pragma unroll
    for (int i = 0; i < 4; i++) af[i]  = *(const short8*)(aB + i * 512);
    #pragma unroll
    for (int j = 0; j < 4; j++) bfr[j] = *(const short8*)(bB + j * 512);
    #pragma unroll
    for (int i = 0; i < 4; i++)
      #pragma unroll
      for (int j = 0; j < 4; j++)
        acc[i][j] = __builtin_amdgcn_mfma_f32_16x16x32_bf16(af[i], bfr[j], acc[i][j], 0, 0, 0);
    __syncthreads();
  }

  if (EPI == 0 || EPI == 3){
    float* Cf = (float*)Cp + (int64_t)z * cZ;
    #pragma unroll
    for (int i = 0; i < 4; i++)
      #pragma unroll
      for (int j = 0; j < 4; j++){
        int64_t gr = m0 + wr * 64 + i * 16 + q * 4;
        int64_t gc = n0 + wc * 64 + j * 16 + c16;
        if (gc < Nvalid){
          #pragma unroll
          for (int r = 0; r < 4; r++){
            float vv = acc[i][j][r];
            if (EPI == 3) vv += auxf1[(gr + r) * ldc + gc] + auxf2[gc];
            Cf[(gr + r) * ldc + gc] = vv;
          }
        }
      }
    return;
  }

  // bf16 output path: per-wave LDS transpose for packed stores
  u16* Cb = (u16*)Cp + (int64_t)z * cZ;
  float* ep = sm.ep[w];
  for (int i = 0; i < 4; i++){
    #pragma unroll
    for (int j = 0; j < 4; j++)
      #pragma unroll
      for (int r = 0; r < 4; r++){
        float vv = acc[i][j][r];
        if (EPI == 1) vv = geluf(vv);
        ep[(q * 4 + r) * 68 + j * 16 + c16] = vv;
      }
    #pragma unroll
    for (int p = 0; p < 4; p++){
      int id = p * 64 + lane;
      int row = id >> 4, cg = id & 15;
      float o0 = ep[row * 68 + cg * 4 + 0];
      float o1 = ep[row * 68 + cg * 4 + 1];
      float o2 = ep[row * 68 + cg * 4 + 2];
      float o3 = ep[row * 68 + cg * 4 + 3];
      int64_t gr = m0 + wr * 64 + i * 16 + row;
      int64_t gc = n0 + wc * 64 + cg * 4;
      if (EPI == 2){
        U2 pv = *(const U2*)(aux1 + gr * ldc + gc);
        o0 *= bf2f((u16)(pv.x & 0xffff)); o1 *= bf2f((u16)(pv.x >> 16));
        o2 *= bf2f((u16)(pv.y & 0xffff)); o3 *= bf2f((u16)(pv.y >> 16));
      }
      if (gc < Nvalid){
        U2 outp;
        outp.x = (u32)f2bf(o0) | ((u32)f2bf(o1) << 16);
        outp.y = (u32)f2bf(o2) | ((u32)f2bf(o3) << 16);
        *(U2*)(Cb + gr * ldc + gc) = outp;
      }
    }
  }
}

// ================= 256x256 8-phase pipelined GEMM (T2+T3+T4+T5) =================
// C[m,n] = sum_k A[m,k]*B[n,k] + auxf1[m,n] + auxf2[n], f32 out.
// 512 threads = 8 waves (2 row-groups x 4 col-groups). BK=64, 2-deep LDS dbuf
// (128 KiB dynamic). 4 phases per K-tile, Gray-code quadrant order
// (0,0)->(0,1)->(1,1)->(1,0): each phase re-reads ONE operand set, so each
// 16KB LDS unit is dead after one phase -> staging tile t+2 into the CURRENT
// buffer is race-free. Counted s_waitcnt vmcnt(6) once per K-tile keeps
// 3 stage-units (6 loads) in flight across the barrier (never drains to 0).
// T2 swizzle: byte ^= (row&7)<<4, applied via pre-swizzled GLOBAL source
// (linear global_load_lds dest) + XOR on the ds_read address.
// Requires: M%256==0, N%256==0, K%128==0.
#define FENCE __builtin_amdgcn_sched_barrier(0)
#define BARX  __builtin_amdgcn_s_barrier()

// one 16KB unit = tile rows [SEL*128, SEL*128+128) of A or B, 2 x 8KB loads.
// SRC must be the per-thread pre-swizzled base (row += lane>>3, col ^= swz).
#define STAGE(SRC, LD, TBASE, SEL, KT)                                          \
  { const u16* _g = (SRC) + (int64_t)(KT) * 64 + (int64_t)((SEL) * 128 + wid * 8) * (LD); \
    u16* _lb = (TBASE) + ((SEL) * 128 + wid * 8) * 64;                          \
    ldsload16(_g, _lb);                                                         \
    ldsload16(_g + (int64_t)64 * (LD), _lb + 64 * 64);                          \
  }

#define MFMAQ(QM, QN, BQ)                                                       \
  __builtin_amdgcn_s_setprio(1);                                                \
  _Pragma("unroll")                                                             \
  for (int mi = 0; mi < 4; mi++)                                                \
    _Pragma("unroll")                                                           \
    for (int ni = 0; ni < 2; ni++){                                             \
      acc[(QM)*4+mi][(QN)*2+ni] = __builtin_amdgcn_mfma_f32_16x16x32_bf16(      \
          af[mi][0], BQ[ni][0], acc[(QM)*4+mi][(QN)*2+ni], 0, 0, 0);            \
      acc[(QM)*4+mi][(QN)*2+ni] = __builtin_amdgcn_mfma_f32_16x16x32_bf16(      \
          af[mi][1], BQ[ni][1], acc[(QM)*4+mi][(QN)*2+ni], 0, 0, 0);            \
    }                                                                           \
  __builtin_amdgcn_s_setprio(0);

#define DO_TILE(T, BUFC, BUFN)                                                  \
  {                                                                             \
    const char* Ac = (const char*)(BUFC);                                       \
    const char* Bc = (const char*)((BUFC) + 16384);                             \
    /* ---- P0: read A(qm=0)+B(qn=0); stage (T+1):B1 -> BUFN ---- */            \
    _Pragma("unroll")                                                           \
    for (int mi = 0; mi < 4; mi++){                                             \
      af[mi][0] = *(const short8*)(Ac + abase + mi * 2048 + kx0);               \
      af[mi][1] = *(const short8*)(Ac + abase + mi * 2048 + kx1);               \
    }                                                                           \
    _Pragma("unroll")                                                           \
    for (int ni = 0; ni < 2; ni++){                                             \
      bq0[ni][0] = *(const short8*)(Bc + bbase + ni * 2048 + kx0);              \
      bq0[ni][1] = *(const short8*)(Bc + bbase + ni * 2048 + kx1);              \
    }                                                                           \
    if ((T) + 1 < NT) STAGE(Bsrc, ldb, (BUFN) + 16384, 1, (T) + 1);             \
    FENCE; BARX; FENCE;                                                         \
    MFMAQ(0, 0, bq0);                                                           \
    FENCE; BARX; FENCE;                                                         \
    /* ---- P1: read B(qn=1); stage (T+2):A0 -> BUFC (region freed at P0) */    \
    _Pragma("unroll")                                                           \
    for (int ni = 0; ni < 2; ni++){                                             \
      bq1[ni][0] = *(const short8*)(Bc + 16384 + bbase + ni * 2048 + kx0);      \
      bq1[ni][1] = *(const short8*)(Bc + 16384 + bbase + ni * 2048 + kx1);      \
    }                                                                           \
    if ((T) + 2 < NT) STAGE(Asrc, lda, (BUFC), 0, (T) + 2);                     \
    FENCE; BARX; FENCE;                                                         \
    MFMAQ(0, 1, bq1);                                                           \
    FENCE; BARX; FENCE;                                                         \
    /* ---- P2: read A(qm=1); stage (T+2):B0 -> BUFC (freed at P0) ---- */      \
    _Pragma("unroll")                                                           \
    for (int mi = 0; mi < 4; mi++){                                             \
      af[mi][0] = *(const short8*)(Ac + 16384 + abase + mi * 2048 + kx0);       \
      af[mi][1] = *(const short8*)(Ac + 16384 + abase + mi * 2048 + kx1);       \
    }                                                                           \
    if ((T) + 2 < NT) STAGE(Bsrc, ldb, (BUFC) + 16384, 0, (T) + 2);             \
    FENCE; BARX; FENCE;                                                         \
    MFMAQ(1, 1, bq1);                                                           \
    FENCE; BARX; FENCE;                                                         \
    /* ---- P3: stage (T+2):A1 -> BUFC (freed at P2); counted vmcnt ---- */     \
    if ((T) + 2 < NT){                                                          \
      STAGE(Asrc, lda, (BUFC), 1, (T) + 2);                                     \
      asm volatile("s_waitcnt vmcnt(6)" ::: "memory");                          \
    } else {                                                                    \
      asm volatile("s_waitcnt vmcnt(0)" ::: "memory");                          \
    }                                                                           \
    FENCE; BARX; FENCE;                                                         \
    MFMAQ(1, 0, bq0);                                                           \
    FENCE; BARX; FENCE;                                                         \
  }

__global__ __launch_bounds__(512) void k_gemm256(
    const u16* __restrict__ A, int64_t lda,
    const u16* __restrict__ B, int64_t ldb,
    float* __restrict__ C, int64_t ldc, int K,
    const float* __restrict__ auxf1, const float* __restrict__ auxf2)
{
  extern __shared__ __align__(16) u16 smd[];   // [2 buf][A|B][256][64] = 128 KiB
  const int tid = threadIdx.x, wid = tid >> 6, lane = tid & 63;
  const int wr = wid >> 2, wc = wid & 3, c16 = lane & 15;

  int bx = blockIdx.x, by = blockIdx.y;        // bijective XCD swizzle
  if ((gridDim.y & 7) == 0 && gridDim.x > 1){
    u32 idx = by * gridDim.x + bx;
    u32 xcd = idx & 7, s = idx >> 3;
    bx = s % gridDim.x;
    by = (s / gridDim.x) * 8 + xcd;
  }
  const int64_t m0 = (int64_t)by * 256;
  const int64_t n0 = (int64_t)bx * 256;
  const int NT = K >> 6;

  // staging: per-thread pre-swizzled global source (linear LDS dest).
  // lane covers row (lane>>3), 16B chunk ((lane&7) ^ (lane>>3)) of a 128B row.
  const int rowin = lane >> 3;
  const int colel = 8 * ((lane & 7) ^ rowin);
  const u16* Asrc = A + (m0 + rowin) * lda + colel;
  const u16* Bsrc = B + (n0 + rowin) * ldb + colel;

  // ds_read swizzled k-offsets (bytes): (k*2) ^ ((row&7)<<4), row&7 == lane&7
  const int kx0 = ((lane >> 4) << 4) ^ ((lane & 7) << 4);
  const int kx1 = kx0 ^ 64;
  const int abase = (wr * 64 + c16) * 128;   // A row bytes (qm=0)
  const int bbase = (wc * 32 + c16) * 128;   // B row bytes (qn=0)

  u16* buf0 = smd;
  u16* buf1 = smd + 32768;

  v4f acc[8][4];
  #pragma unroll
  for (int i = 0; i < 8; i++)
    #pragma unroll
    for (int j = 0; j < 4; j++) acc[i][j] = (v4f)0.0f;

  short8 af[4][2], bq0[2][2], bq1[2][2];

  // prologue: tile0 fully (8 loads) + tile1 A0,B0,A1 (6 loads); confirm tile0,
  // keep 3 units in flight -> steady-state invariant for the main loop.
  STAGE(Asrc, lda, buf0,         0, 0);
  STAGE(Bsrc, ldb, buf0 + 16384, 0, 0);
  STAGE(Bsrc, ldb, buf0 + 16384, 1, 0);
  STAGE(Asrc, lda, buf0,         1, 0);
  if (NT > 1){
    STAGE(Asrc, lda, buf1,         0, 1);
    STAGE(Bsrc, ldb, buf1 + 16384, 0, 1);
    STAGE(Asrc, lda, buf1,         1, 1);
    asm volatile("s_waitcnt vmcnt(6)" ::: "memory");
  } else {
    asm volatile("s_waitcnt vmcnt(0)" ::: "memory");
  }
  FENCE; BARX; FENCE;

  for (int t = 0; t < NT; t += 2){   // NT must be even
    DO_TILE(t,     buf0, buf1)
    DO_TILE(t + 1, buf1, buf0)
  }

  // epilogue: C = acc + auxf1 + auxf2 (f32)
  const int q4 = (lane >> 4) << 2;
  #pragma unroll
  for (int qm = 0; qm < 2; qm++)
    #pragma unroll
    for (int mi = 0; mi < 4; mi++){
      int64_t gr = m0 + qm * 128 + wr * 64 + mi * 16 + q4;
      #pragma unroll
      for (int qn = 0; qn < 2; qn++)
        #pragma unroll
        for (int ni = 0; ni < 2; ni++){
          int64_t gc = n0 + qn * 128 + wc * 32 + ni * 16 + c16;
          v4f a = acc[qm * 4 + mi][qn * 2 + ni];
          float bo = auxf2[gc];
          #pragma unroll
          for (int r = 0; r < 4; r++)
            C[(gr + r) * ldc + gc] = a[r] + auxf1[(gr + r) * ldc + gc] + bo;
        }
    }
}

extern "C" void kernel_launch(void* const* d_in, const int* in_sizes, int n_in,
                              void* d_out, int out_size, void* d_ws, size_t ws_size,
                              hipStream_t stream) {
  (void)in_sizes; (void)n_in; (void)out_size; (void)ws_size;
  const float* x      = (const float*)d_in[0];
  const float* norm_g = (const float*)d_in[1];
  const float* norm_b = (const float*)d_in[2];
  const float* W_v    = (const float*)d_in[3];
  const float* W_u    = (const float*)d_in[4];
  const float* W_uc   = (const float*)d_in[5];
  const float* W_o    = (const float*)d_in[6];
  const float* b_o    = (const float*)d_in[7];
  const float* dss_g  = (const float*)d_in[8];
  const float* dss_b  = (const float*)d_in[9];
  const float* lam_re = (const float*)d_in[10];
  const float* lam_im = (const float*)d_in[11];
  const float* C_re   = (const float*)d_in[12];
  const float* C_im   = (const float*)d_in[13];
  const float* D_skip = (const float*)d_in[14];

  // ---- d_out (67.1 MB f32) doubles as scratch for xn + 2 bf16 weights (dead before final GEMM) ----
  char* ob = (char*)d_out;
  u16* xn    = (u16*)(ob);                         // 33,554,432 B
  u16* Wv_b  = (u16*)(ob + 33554432ull);           //  2,097,152 B
  u16* Wu_b  = (u16*)(ob + 35651584ull);           //    131,072 B

  // ---- workspace layout (aliased by lifetime), total ~224 MiB ----
  char* ws = (char*)d_ws;
  const size_t R1      = 134217728ull;             // after v: u -> (Rcat | WT)
  const size_t OFF_UN  = R1 + 33554432ull;
  const size_t OFF_UNT = OFF_UN + 8388608ull;      // unT, later y
  const size_t OFF_R2  = OFF_UNT + 8388608ull;     // S -> (Ycross | Yloc)
  const size_t OFF_TAB = OFF_R2 + 33554432ull;

  u16*  v     = (u16*)(ws + 0);                    // [32768,2048] bf16
  u16*  u     = (u16*)(ws + R1);
  u16*  Rcat  = (u16*)(ws + R1);                   // 16.8 MB
  u16*  WT    = (u16*)(ws + R1 + 16777216ull);     // 16.8 MB
  u16*  un    = (u16*)(ws + OFF_UN);
  u16*  unT   = (u16*)(ws + OFF_UNT);
  u16*  y     = (u16*)(ws + OFF_UNT);
  float* S    = (float*)(ws + OFF_R2);
  float* Ycross = (float*)(ws + OFF_R2);
  float* Yloc = (float*)(ws + OFF_R2 + 16777216ull);
  char* tp = ws + OFF_TAB;
  u16*  ZC   = (u16*)tp;            tp += 1048576;
  u16*  PC   = (u16*)tp;            tp += 1048576;
  u16*  VC   = (u16*)tp;            tp += 1048576;
  u16*  ccat = (u16*)tp;            tp += 262144;
  float* cre = (float*)tp;          tp += 262144;
  float* cim = (float*)tp;          tp += 262144;
  float* zT  = (float*)tp;          tp += 4096;
  float* kern= (float*)tp;          tp += 262144;
  u16*  Wo_b = (u16*)tp;            tp += 2097152;
  u16*  Wuc_b= (u16*)tp;            tp += 524288;

  // weight conversions (f32 -> bf16), one launch
  k_cvt4<<<9472, 256, 0, stream>>>(W_v, Wv_b, 2048 * 512,
                                   W_u, Wu_b, 128 * 512,
                                   W_uc, Wuc_b, 2048 * 128,
                                   W_o, Wo_b, 512 * 2048);

  k_ln1<<<BL, 256, 0, stream>>>(x, norm_g, norm_b, xn);
  k_prep<<<512, 512, 0, stream>>>(lam_re, lam_im, C_re, C_im, ZC, PC, VC, ccat, cre, cim, zT);

  // v = gelu(xn @ W_v^T)   [32768,2048] bf16
  k_gemm<1><<<dim3(16, 256, 1), 256, 0, stream>>>(xn, 512, 0, Wv_b, 512, 0, v, 2048, 0, 512, 2048, nullptr, nullptr, nullptr);
  // u = gelu(xn @ W_u^T)   [32768,128] bf16
  k_gemm<1><<<dim3(1, 256, 1), 256, 0, stream>>>(xn, 512, 0, Wu_b, 512, 0, u, 128, 0, 512, 128, nullptr, nullptr, nullptr);
  k_ln2<<<BL / 4, 256, 0, stream>>>(u, dss_g, dss_b, un);
  k_transpose<<<512, 256, 0, stream>>>(un, unT);

  // kern[d,h] = Re(c_h . z^d) : A=VC [512,1024], B=ccat [128,1024] -> f32 [512,128]
  k_gemm<0><<<dim3(1, 4, 1), 256, 0, stream>>>(VC, 1024, 0, ccat, 1024, 0, kern, 128, 0, 1024, 128, nullptr, nullptr, nullptr);
  k_rcat<<<16384, 512, 0, stream>>>(kern, Rcat);

  // chunk states: S[m,n'] = sum_i unT[m,i]*ZC[n',i]  [8192,1024] f32
  k_gemm<0><<<dim3(8, 64, 1), 256, 0, stream>>>(unT, 512, 0, ZC, 512, 0, S, 1024, 0, 512, 1024, nullptr, nullptr, nullptr);
  k_scan<<<1024, 256, 0, stream>>>(S, cre, cim, zT, WT);
  // injection: Ycross[i,m] = sum_n' PC[i,n']*WT[m,n']  [512,8192] f32
  k_gemm<0><<<dim3(64, 4, 1), 256, 0, stream>>>(PC, 1024, 0, WT, 1024, 0, Ycross, 8192, 0, 1024, 8192, nullptr, nullptr, nullptr);
  // local conv via block-Toeplitz, single launch (TRI mode: by = i_blk)
  k_gemm<0, true><<<dim3(1, 4, 128), 256, 0, stream>>>(
      Rcat, 512, 65536, unT, 65536, 512, Yloc, 64, 32768, 512, 64, nullptr, nullptr, nullptr);
  k_assemble<<<16384, 256, 0, stream>>>(Yloc, Ycross, un, D_skip, y);

  // uc = y @ W_uc^T, fused t = uc*v (in place over v)
  k_gemm<2><<<dim3(16, 256, 1), 256, 0, stream>>>(y, 128, 0, Wuc_b, 128, 0, v, 2048, 0, 128, 2048, v, nullptr, nullptr);
  // out = t @ W_o^T + b_o + x   (f32 out) — 256x256 8-phase pipelined kernel
  k_gemm256<<<dim3(2, 128), 512, 131072, stream>>>(v, 2048, Wo_b, 2048, (float*)d_out, 512, 2048, x, b_o);
}

// Round 2
// 590.144 us; speedup vs baseline: 1.2895x; 1.1317x over previous
//
#include <hip/hip_runtime.h>
#include <math.h>
#include <stdint.h>

typedef unsigned short u16;
typedef unsigned int   u32;
typedef short short8 __attribute__((ext_vector_type(8)));
typedef float v4f    __attribute__((ext_vector_type(4)));

#define DEVI static __device__ __forceinline__

struct __align__(8)  U2 { u32 x, y; };
struct __align__(16) U4 { u32 x, y, z, w; };

static const int BB = 4, LL = 8192;
static const int BL = BB * LL;           // 32768 rows

DEVI float bf2f(u16 u){ u32 v = ((u32)u) << 16; float f; __builtin_memcpy(&f, &v, 4); return f; }
DEVI u16  f2bf(float f){ u32 u; __builtin_memcpy(&u, &f, 4); return (u16)((u + 0x7fffu + ((u >> 16) & 1u)) >> 16); }

// fast exact-gelu: erf via Abramowitz-Stegun 7.1.26 (max abs err 1.5e-7,
// far below bf16 rounding). ~15 VALU vs libm erff's ~100+.
DEVI float geluf(float x){
  float z = fabsf(x) * 0.7071067811865475f;
  float t = __builtin_amdgcn_rcpf(1.0f + 0.3275911f * z);
  float p = t * (0.254829592f + t * (-0.284496736f + t * (1.421413741f +
            t * (-1.453152027f + t * 1.061405429f))));
  float e = __builtin_amdgcn_exp2f(z * z * -1.4426950408889634f);
  float er = 1.0f - p * e;
  float s = (x < 0.0f) ? -er : er;
  return 0.5f * x * (1.0f + s);
}

DEVI void ldsload16(const void* g, void* l){
  __builtin_amdgcn_global_load_lds(
      (const __attribute__((address_space(1))) u32*)(uintptr_t)g,
      (__attribute__((address_space(3)))  u32*)(u32)(uintptr_t)l,
      16, 0, 0);
}

// ---------------- f32 -> bf16 convert, 4 tensors in one launch ----------------
__global__ __launch_bounds__(256) void k_cvt4(
    const float* __restrict__ s0, u16* __restrict__ d0, int n0,
    const float* __restrict__ s1, u16* __restrict__ d1, int n1,
    const float* __restrict__ s2, u16* __restrict__ d2, int n2,
    const float* __restrict__ s3, u16* __restrict__ d3, int n3){
  int i = blockIdx.x * 256 + threadIdx.x;
  if (i < n0){ d0[i] = f2bf(s0[i]); return; }
  i -= n0;
  if (i < n1){ d1[i] = f2bf(s1[i]); return; }
  i -= n1;
  if (i < n2){ d2[i] = f2bf(s2[i]); return; }
  i -= n2;
  if (i < n3){ d3[i] = f2bf(s3[i]); }
}

// ---------------- LayerNorm over 512 (f32 in, bf16 out) ----------------
__global__ __launch_bounds__(256) void k_ln1(const float* __restrict__ x, const float* __restrict__ g,
                                             const float* __restrict__ b, u16* __restrict__ xn){
  int row = blockIdx.x, t = threadIdx.x;
  const float2* xr = (const float2*)(x + (int64_t)row * 512);
  float2 p = xr[t];
  float s = p.x + p.y, ss = p.x * p.x + p.y * p.y;
  for (int off = 32; off; off >>= 1){ s += __shfl_down(s, off); ss += __shfl_down(ss, off); }
  __shared__ float red[8];
  int w = t >> 6, lane = t & 63;
  if (!lane){ red[w] = s; red[4 + w] = ss; }
  __syncthreads();
  s  = red[0] + red[1] + red[2] + red[3];
  ss = red[4] + red[5] + red[6] + red[7];
  float m = s * (1.0f / 512.0f), var = ss * (1.0f / 512.0f) - m * m;
  float rs = rsqrtf(var + 1e-5f);
  float2 gv = ((const float2*)g)[t], bv = ((const float2*)b)[t];
  float r0 = (p.x - m) * rs * gv.x + bv.x;
  float r1 = (p.y - m) * rs * gv.y + bv.y;
  ((u32*)(xn + (int64_t)row * 512))[t] = (u32)f2bf(r0) | ((u32)f2bf(r1) << 16);
}

// ---------------- LayerNorm over 128 (bf16 in, f32 params, bf16 out) ----------------
__global__ __launch_bounds__(256) void k_ln2(const u16* __restrict__ u, const float* __restrict__ g,
                                             const float* __restrict__ b, u16* __restrict__ un){
  int row = blockIdx.x * 4 + (threadIdx.x >> 6);
  int lane = threadIdx.x & 63;
  const u32* ur = (const u32*)(u + (int64_t)row * 128);
  u32 pv = ur[lane];
  float a = bf2f((u16)(pv & 0xffff)), c = bf2f((u16)(pv >> 16));
  float s = a + c, ss = a * a + c * c;
  for (int off = 32; off; off >>= 1){ s += __shfl_xor(s, off); ss += __shfl_xor(ss, off); }
  float m = s * (1.0f / 128.0f), var = ss * (1.0f / 128.0f) - m * m;
  float rs = rsqrtf(var + 1e-5f);
  float2 gv = ((const float2*)g)[lane], bv = ((const float2*)b)[lane];
  float r0 = (a - m) * rs * gv.x + bv.x;
  float r1 = (c - m) * rs * gv.y + bv.y;
  ((u32*)(un + (int64_t)row * 128))[lane] = (u32)f2bf(r0) | ((u32)f2bf(r1) << 16);
}

// ---------------- transpose un[BL,128] -> unT[(b,c,h), i] [8192,512] ----------------
__global__ __launch_bounds__(256) void k_transpose(const u16* __restrict__ un, u16* __restrict__ unT){
  int bc = blockIdx.x >> 3, it = blockIdx.x & 7;
  int b = bc >> 4, cc = bc & 15;
  __shared__ __align__(16) u16 tile[64][128];
  const u16* src = un + ((int64_t)(b * 8192 + cc * 512 + it * 64)) * 128;
  int t = threadIdx.x;
  for (int p = 0; p < 4; p++){
    int id = p * 256 + t; int ri = id >> 4, seg = id & 15;
    *(U4*)&tile[ri][seg * 8] = *(const U4*)(src + (int64_t)ri * 128 + seg * 8);
  }
  __syncthreads();
  u16* dst = unT + ((int64_t)(bc * 128)) * 512 + it * 64;
  for (int p = 0; p < 4; p++){
    int id = p * 256 + t; int h = id >> 3, seg = id & 7;
    U4 pk; u16* pv = (u16*)&pk;
    for (int k2 = 0; k2 < 8; k2++) pv[k2] = tile[seg * 8 + k2][h];
    *(U4*)(dst + (int64_t)h * 512 + seg * 8) = pk;
  }
}

// ---------------- DSS tables (f32 params) ----------------
__global__ __launch_bounds__(512) void k_prep(const float* lam_re, const float* lam_im,
    const float* C_re, const float* C_im,
    u16* ZC, u16* PC, u16* VC, u16* ccat, float* cre, float* cim, float* zT){
  int n = blockIdx.x, t = threadIdx.x;
  float lr = -expf(lam_re[n]);
  float li =  expf(lam_im[n]);
  float mag = expf(lr * (float)t), ph = li * (float)t;
  float er = mag * cosf(ph), ei = mag * sinf(ph);
  ZC[(int64_t)n * 512 + (511 - t)]         = f2bf(er);
  ZC[(int64_t)(512 + n) * 512 + (511 - t)] = f2bf(ei);
  VC[(int64_t)t * 1024 + n]       = f2bf(er);
  VC[(int64_t)t * 1024 + 512 + n] = f2bf(-ei);
  float mag2 = expf(lr * (float)(t + 1)), ph2 = li * (float)(t + 1);
  PC[(int64_t)t * 1024 + n]       = f2bf(mag2 * cosf(ph2));
  PC[(int64_t)t * 1024 + 512 + n] = f2bf(-mag2 * sinf(ph2));
  if (t == 0){
    float m5 = expf(lr * 512.0f), p5 = li * 512.0f;
    zT[n] = m5 * cosf(p5); zT[512 + n] = m5 * sinf(p5);
  }
  if (t < 128){
    float e1m = expf(lr);
    float e1r = e1m * cosf(li), e1i = e1m * sinf(li);
    float nr = e1r - 1.0f, ni = e1i;
    float d2 = lr * lr + li * li;
    float qr = (nr * lr + ni * li) / d2, qi = (ni * lr - nr * li) / d2;
    float Cr = C_re[t * 512 + n], Ci = C_im[t * 512 + n];
    float vr = Cr * qr - Ci * qi, vi = Cr * qi + Ci * qr;
    cre[t * 512 + n] = vr; cim[t * 512 + n] = vi;
    ccat[(int64_t)t * 1024 + n] = f2bf(vr); ccat[(int64_t)t * 1024 + 512 + n] = f2bf(vi);
  }
}

// ---------------- block-Toeplitz build ----------------
__global__ __launch_bounds__(512) void k_rcat(const float* __restrict__ kern, u16* __restrict__ Rcat){
  int h = blockIdx.x >> 7, a = blockIdx.x & 127;
  int kcol = threadIdx.x;
  int d = 3 - (kcol >> 7);
  int delay = d * 128 + a - (kcol & 127);
  float val = (delay >= 0 && delay < 512) ? kern[delay * 128 + h] : 0.0f;
  Rcat[((int64_t)(h * 128 + a)) * 512 + kcol] = f2bf(val);
}

// ---------------- chunk scan + W = c * Scarry ----------------
__global__ __launch_bounds__(256) void k_scan(const float* __restrict__ S, const float* __restrict__ cre,
    const float* __restrict__ cim, const float* __restrict__ zT, u16* __restrict__ WT){
  int tid = blockIdx.x * 256 + threadIdx.x;   // 262144
  int n = tid & 511, bh = tid >> 9, b = bh >> 7, h = bh & 127;
  float cr = cre[h * 512 + n], ci = cim[h * 512 + n];
  float zr = zT[n], zi = zT[512 + n];
  float sR = 0.0f, sI = 0.0f;
  for (int cc = 0; cc < 16; cc++){
    int64_t m = (int64_t)(b * 16 + cc) * 128 + h;
    float wR = cr * sR - ci * sI, wI = cr * sI + ci * sR;
    WT[m * 1024 + n] = f2bf(wR);
    WT[m * 1024 + 512 + n] = f2bf(wI);
    float aR = S[m * 1024 + n], aI = S[m * 1024 + 512 + n];
    float nR = zr * sR - zi * sI + aR;
    sI = zr * sI + zi * sR + aI;
    sR = nR;
  }
}

// ---------------- y = Yloc + Ycross + un*D_skip ----------------
__global__ __launch_bounds__(256) void k_assemble(const float* __restrict__ Yloc, const float* __restrict__ Ycross,
    const u16* __restrict__ un, const float* __restrict__ Dskip, u16* __restrict__ y){
  int64_t e = (int64_t)blockIdx.x * 256 + threadIdx.x;
  int h = (int)(e & 127); int64_t bl = e >> 7;
  int b = (int)(bl >> 13), l = (int)(bl & 8191);
  int cc = l >> 9, ii = l & 511, bc = b * 16 + cc;
  float val = Yloc[((int64_t)h * 512 + ii) * 64 + bc]
            + Ycross[(int64_t)ii * 8192 + (int64_t)bc * 128 + h]
            + bf2f(un[e]) * Dskip[h];
  y[e] = f2bf(val);
}

// ---------------- generic BT GEMM: C[m,n] = sum_k A[m,k]*B[n,k] ----------------
// EPI: 0 = f32 direct store; 1 = gelu->bf16
// TRI: block-Toeplitz mode (A has 128 rows; per row-block ib=by: A base shift
//      (3-ib)*128, K_eff=(ib+1)*128). Yloc local-conv in ONE launch.
template<int EPI, bool TRI = false>
__global__ __launch_bounds__(256) void k_gemm(
    const u16* __restrict__ A, int64_t lda, int64_t aZ,
    const u16* __restrict__ B, int64_t ldb, int64_t bZ,
    void* Cp, int64_t ldc, int64_t cZ,
    int K, int Nvalid,
    const u16* aux1, const float* auxf1, const float* auxf2)
{
  __shared__ union __align__(16) SMU { u16 st[2][4096]; float ep[4][1088]; } sm;
  const int tid = threadIdx.x;
  const int lane = tid & 63, w = tid >> 6;
  const int wr = w >> 1, wc = w & 1, q = lane >> 4, c16 = lane & 15;
  const int sRow = lane >> 2, sSeg = lane & 3;
  const int z = blockIdx.z;

  int bx = blockIdx.x, by = blockIdx.y;
  if (!TRI && (gridDim.y & 7) == 0 && gridDim.x > 1){
    u32 idx = by * gridDim.x + bx;
    u32 xcd = idx & 7, s = idx >> 3;
    bx = s % gridDim.x;
    by = (s / gridDim.x) * 8 + xcd;
  }
  const int64_t m0 = (int64_t)by * 128;
  const int64_t n0 = (int64_t)bx * 128;

  const u16* Ab = A + (int64_t)z * aZ;
  const u16* Bp = B + (int64_t)z * bZ;
  int Keff = K;
  if (TRI){
    Ab += 384 - m0;              // (3-ib)*128 column shift
    Keff = (int)(m0 + 128);      // (ib+1)*128
  }

  v4f acc[4][4];
  #pragma unroll
  for (int i = 0; i < 4; i++)
    #pragma unroll
    for (int j = 0; j < 4; j++)
      acc[i][j] = (v4f)0.0f;

  for (int k0 = 0; k0 < Keff; k0 += 32){
    #pragma unroll
    for (int half = 0; half < 2; half++){
      int r0 = (half * 4 + w) * 16;
      int64_t arow = (TRI ? (int64_t)0 : m0) + r0 + sRow;
      ldsload16(Ab + arow * lda + k0 + sSeg * 8, &sm.st[0][r0 * 32]);
      int64_t brow = n0 + r0 + sRow;
      if (brow >= Nvalid) brow = Nvalid - 1;
      ldsload16(Bp + brow * ldb + k0 + sSeg * 8, &sm.st[1][r0 * 32]);
    }
    __syncthreads();
    short8 af[4], bfr[4];
    const u16* aB = &sm.st[0][(wr * 64 + c16) * 32 + q * 8];
    const u16* bB = &sm.st[1][(wc * 64 + c16) * 32 + q * 8];
    #pragma unroll
    for (int i = 0; i < 4; i++) af[i]  = *(const short8*)(aB + i * 512);
    #pragma unroll
    for (int j = 0; j < 4; j++) bfr[j] = *(const short8*)(bB + j * 512);
    #pragma unroll
    for (int i = 0; i < 4; i++)
      #pragma unroll
      for (int j = 0; j < 4; j++)
        acc[i][j] = __builtin_amdgcn_mfma_f32_16x16x32_bf16(af[i], bfr[j], acc[i][j], 0, 0, 0);
    __syncthreads();
  }

  if (EPI == 0){
    float* Cf = (float*)Cp + (int64_t)z * cZ;
    #pragma unroll
    for (int i = 0; i < 4; i++)
      #pragma unroll
      for (int j = 0; j < 4; j++){
        int64_t gr = m0 + wr * 64 + i * 16 + q * 4;
        int64_t gc = n0 + wc * 64 + j * 16 + c16;
        if (gc < Nvalid){
          #pragma unroll
          for (int r = 0; r < 4; r++)
            Cf[(gr + r) * ldc + gc] = acc[i][j][r];
        }
      }
    return;
  }

  // bf16 output path: per-wave LDS transpose for packed stores
  u16* Cb = (u16*)Cp + (int64_t)z * cZ;
  float* ep = sm.ep[w];
  for (int i = 0; i < 4; i++){
    #pragma unroll
    for (int j = 0; j < 4; j++)
      #pragma unroll
      for (int r = 0; r < 4; r++){
        float vv = acc[i][j][r];
        if (EPI == 1) vv = geluf(vv);
        ep[(q * 4 + r) * 68 + j * 16 + c16] = vv;
      }
    #pragma unroll
    for (int p = 0; p < 4; p++){
      int id = p * 64 + lane;
      int row = id >> 4, cg = id & 15;
      float o0 = ep[row * 68 + cg * 4 + 0];
      float o1 = ep[row * 68 + cg * 4 + 1];
      float o2 = ep[row * 68 + cg * 4 + 2];
      float o3 = ep[row * 68 + cg * 4 + 3];
      int64_t gr = m0 + wr * 64 + i * 16 + row;
      int64_t gc = n0 + wc * 64 + cg * 4;
      if (gc < Nvalid){
        U2 outp;
        outp.x = (u32)f2bf(o0) | ((u32)f2bf(o1) << 16);
        outp.y = (u32)f2bf(o2) | ((u32)f2bf(o3) << 16);
        *(U2*)(Cb + gr * ldc + gc) = outp;
      }
    }
  }
}

// ================= 256x256 8-phase pipelined GEMM (T2+T3+T4+T5) =================
// C[m,n] = sum_k A[m,k]*B[n,k]; EPI: 0 = f32 out (+auxf1[m,n]+auxf2[n]),
// 1 = gelu -> bf16, 2 = *aux1[m,n](bf16) -> bf16.
// 512 threads = 8 waves (2 row-groups x 4 col-groups). BK=64, 2-deep LDS dbuf
// (128 KiB dynamic). 4 phases per K-tile, Gray-code quadrant order; counted
// s_waitcnt vmcnt(6) once per K-tile (3 stage-units in flight, never 0).
// T2 swizzle: byte ^= (row&7)<<4 via pre-swizzled GLOBAL source + XOR ds_read.
// Requires: M%256==0, N%256==0, K%128==0 (NT even).
#define FENCE __builtin_amdgcn_sched_barrier(0)
#define BARX  __builtin_amdgcn_s_barrier()

#define STAGE(SRC, LD, TBASE, SEL, KT)                                          \
  { const u16* _g = (SRC) + (int64_t)(KT) * 64 + (int64_t)((SEL) * 128 + wid * 8) * (LD); \
    u16* _lb = (TBASE) + ((SEL) * 128 + wid * 8) * 64;                          \
    ldsload16(_g, _lb);                                                         \
    ldsload16(_g + (int64_t)64 * (LD), _lb + 64 * 64);                          \
  }

#define MFMAQ(QM, QN, BQ)                                                       \
  __builtin_amdgcn_s_setprio(1);                                                \
  _Pragma("unroll")                                                             \
  for (int mi = 0; mi < 4; mi++)                                                \
    _Pragma("unroll")                                                           \
    for (int ni = 0; ni < 2; ni++){                                             \
      acc[(QM)*4+mi][(QN)*2+ni] = __builtin_amdgcn_mfma_f32_16x16x32_bf16(      \
          af[mi][0], BQ[ni][0], acc[(QM)*4+mi][(QN)*2+ni], 0, 0, 0);            \
      acc[(QM)*4+mi][(QN)*2+ni] = __builtin_amdgcn_mfma_f32_16x16x32_bf16(      \
          af[mi][1], BQ[ni][1], acc[(QM)*4+mi][(QN)*2+ni], 0, 0, 0);            \
    }                                                                           \
  __builtin_amdgcn_s_setprio(0);

#define DO_TILE(T, BUFC, BUFN)                                                  \
  {                                                                             \
    const char* Ac = (const char*)(BUFC);                                       \
    const char* Bc = (const char*)((BUFC) + 16384);                             \
    _Pragma("unroll")                                                           \
    for (int mi = 0; mi < 4; mi++){                                             \
      af[mi][0] = *(const short8*)(Ac + abase + mi * 2048 + kx0);               \
      af[mi][1] = *(const short8*)(Ac + abase + mi * 2048 + kx1);               \
    }                                                                           \
    _Pragma("unroll")                                                           \
    for (int ni = 0; ni < 2; ni++){                                             \
      bq0[ni][0] = *(const short8*)(Bc + bbase + ni * 2048 + kx0);              \
      bq0[ni][1] = *(const short8*)(Bc + bbase + ni * 2048 + kx1);              \
    }                                                                           \
    if ((T) + 1 < NT) STAGE(Bsrc, ldb, (BUFN) + 16384, 1, (T) + 1);             \
    FENCE; BARX; FENCE;                                                         \
    MFMAQ(0, 0, bq0);                                                           \
    FENCE; BARX; FENCE;                                                         \
    _Pragma("unroll")                                                           \
    for (int ni = 0; ni < 2; ni++){                                             \
      bq1[ni][0] = *(const short8*)(Bc + 16384 + bbase + ni * 2048 + kx0);      \
      bq1[ni][1] = *(const short8*)(Bc + 16384 + bbase + ni * 2048 + kx1);      \
    }                                                                           \
    if ((T) + 2 < NT) STAGE(Asrc, lda, (BUFC), 0, (T) + 2);                     \
    FENCE; BARX; FENCE;                                                         \
    MFMAQ(0, 1, bq1);                                                           \
    FENCE; BARX; FENCE;                                                         \
    _Pragma("unroll")                                                           \
    for (int mi = 0; mi < 4; mi++){                                             \
      af[mi][0] = *(const short8*)(Ac + 16384 + abase + mi * 2048 + kx0);       \
      af[mi][1] = *(const short8*)(Ac + 16384 + abase + mi * 2048 + kx1);       \
    }                                                                           \
    if ((T) + 2 < NT) STAGE(Bsrc, ldb, (BUFC) + 16384, 0, (T) + 2);             \
    FENCE; BARX; FENCE;                                                         \
    MFMAQ(1, 1, bq1);                                                           \
    FENCE; BARX; FENCE;                                                         \
    if ((T) + 2 < NT){                                                          \
      STAGE(Asrc, lda, (BUFC), 1, (T) + 2);                                     \
      asm volatile("s_waitcnt vmcnt(6)" ::: "memory");                          \
    } else {                                                                    \
      asm volatile("s_waitcnt vmcnt(0)" ::: "memory");                          \
    }                                                                           \
    FENCE; BARX; FENCE;                                                         \
    MFMAQ(1, 0, bq0);                                                           \
    FENCE; BARX; FENCE;                                                         \
  }

template<int EPI>
__global__ __launch_bounds__(512) void k_gemm256(
    const u16* __restrict__ A, int64_t lda,
    const u16* __restrict__ B, int64_t ldb,
    void* __restrict__ Cp, int64_t ldc, int K,
    const u16* __restrict__ aux1,
    const float* __restrict__ auxf1, const float* __restrict__ auxf2)
{
  extern __shared__ __align__(16) u16 smd[];   // [2 buf][A|B][256][64] = 128 KiB
  const int tid = threadIdx.x, wid = tid >> 6, lane = tid & 63;
  const int wr = wid >> 2, wc = wid & 3, c16 = lane & 15;
  const int q4 = (lane >> 4) << 2;

  int bx = blockIdx.x, by = blockIdx.y;        // bijective XCD swizzle
  if ((gridDim.y & 7) == 0 && gridDim.x > 1){
    u32 idx = by * gridDim.x + bx;
    u32 xcd = idx & 7, s = idx >> 3;
    bx = s % gridDim.x;
    by = (s / gridDim.x) * 8 + xcd;
  }
  const int64_t m0 = (int64_t)by * 256;
  const int64_t n0 = (int64_t)bx * 256;
  const int NT = K >> 6;

  // staging: per-thread pre-swizzled global source (linear LDS dest).
  const int rowin = lane >> 3;
  const int colel = 8 * ((lane & 7) ^ rowin);
  const u16* Asrc = A + (m0 + rowin) * lda + colel;
  const u16* Bsrc = B + (n0 + rowin) * ldb + colel;

  // ds_read swizzled k-offsets (bytes): (k*2) ^ ((row&7)<<4)
  const int kx0 = ((lane >> 4) << 4) ^ ((lane & 7) << 4);
  const int kx1 = kx0 ^ 64;
  const int abase = (wr * 64 + c16) * 128;   // A row bytes (qm=0)
  const int bbase = (wc * 32 + c16) * 128;   // B row bytes (qn=0)

  u16* buf0 = smd;
  u16* buf1 = smd + 32768;

  v4f acc[8][4];
  #pragma unroll
  for (int i = 0; i < 8; i++)
    #pragma unroll
    for (int j = 0; j < 4; j++) acc[i][j] = (v4f)0.0f;

  short8 af[4][2], bq0[2][2], bq1[2][2];

  // prologue: tile0 fully (8 loads) + tile1 A0,B0,A1 (6 loads)
  STAGE(Asrc, lda, buf0,         0, 0);
  STAGE(Bsrc, ldb, buf0 + 16384, 0, 0);
  STAGE(Bsrc, ldb, buf0 + 16384, 1, 0);
  STAGE(Asrc, lda, buf0,         1, 0);
  if (NT > 1){
    STAGE(Asrc, lda, buf1,         0, 1);
    STAGE(Bsrc, ldb, buf1 + 16384, 0, 1);
    STAGE(Asrc, lda, buf1,         1, 1);
    asm volatile("s_waitcnt vmcnt(6)" ::: "memory");
  } else {
    asm volatile("s_waitcnt vmcnt(0)" ::: "memory");
  }
  FENCE; BARX; FENCE;

  for (int t = 0; t < NT; t += 2){   // NT must be even
    DO_TILE(t,     buf0, buf1)
    DO_TILE(t + 1, buf1, buf0)
  }

  if (EPI == 0){
    // epilogue: C = acc + auxf1 + auxf2 (f32)
    float* C = (float*)Cp;
    #pragma unroll
    for (int qm = 0; qm < 2; qm++)
      #pragma unroll
      for (int mi = 0; mi < 4; mi++){
        int64_t gr = m0 + qm * 128 + wr * 64 + mi * 16 + q4;
        #pragma unroll
        for (int qn = 0; qn < 2; qn++)
          #pragma unroll
          for (int ni = 0; ni < 2; ni++){
            int64_t gc = n0 + qn * 128 + wc * 32 + ni * 16 + c16;
            v4f a = acc[qm * 4 + mi][qn * 2 + ni];
            float bo = auxf2[gc];
            #pragma unroll
            for (int r = 0; r < 4; r++)
              C[(gr + r) * ldc + gc] = a[r] + auxf1[(gr + r) * ldc + gc] + bo;
          }
      }
    return;
  }

  // bf16 epilogue: per-wave LDS transpose (stride 33 -> conflict-light),
  // packed 16B stores. LDS staging bufs are dead after the final barrier.
  u16* Cb = (u16*)Cp;
  float* scr = (float*)smd + wid * 528;        // 16x33 f32 per wave
  const int erow = lane >> 2, eseg = lane & 3;
  #pragma unroll
  for (int qm = 0; qm < 2; qm++)
    #pragma unroll
    for (int mi = 0; mi < 4; mi++)
      #pragma unroll
      for (int qn = 0; qn < 2; qn++){
        #pragma unroll
        for (int ni = 0; ni < 2; ni++){
          v4f a = acc[qm * 4 + mi][qn * 2 + ni];
          #pragma unroll
          for (int r = 0; r < 4; r++){
            float vv = a[r];
            if (EPI == 1) vv = geluf(vv);
            scr[(q4 + r) * 33 + ni * 16 + c16] = vv;
          }
        }
        float o[8];
        #pragma unroll
        for (int kq = 0; kq < 8; kq++) o[kq] = scr[erow * 33 + eseg * 8 + kq];
        int64_t gr = m0 + qm * 128 + wr * 64 + mi * 16 + erow;
        int64_t gc = n0 + qn * 128 + wc * 32 + eseg * 8;
        if (EPI == 2){
          U4 pv = *(const U4*)(aux1 + gr * ldc + gc);
          const u16* pp = (const u16*)&pv;
          #pragma unroll
          for (int kq = 0; kq < 8; kq++) o[kq] *= bf2f(pp[kq]);
        }
        U4 outp; u16* op = (u16*)&outp;
        #pragma unroll
        for (int kq = 0; kq < 8; kq++) op[kq] = f2bf(o[kq]);
        *(U4*)(Cb + gr * ldc + gc) = outp;
      }
}

extern "C" void kernel_launch(void* const* d_in, const int* in_sizes, int n_in,
                              void* d_out, int out_size, void* d_ws, size_t ws_size,
                              hipStream_t stream) {
  (void)in_sizes; (void)n_in; (void)out_size; (void)ws_size;
  const float* x      = (const float*)d_in[0];
  const float* norm_g = (const float*)d_in[1];
  const float* norm_b = (const float*)d_in[2];
  const float* W_v    = (const float*)d_in[3];
  const float* W_u    = (const float*)d_in[4];
  const float* W_uc   = (const float*)d_in[5];
  const float* W_o    = (const float*)d_in[6];
  const float* b_o    = (const float*)d_in[7];
  const float* dss_g  = (const float*)d_in[8];
  const float* dss_b  = (const float*)d_in[9];
  const float* lam_re = (const float*)d_in[10];
  const float* lam_im = (const float*)d_in[11];
  const float* C_re   = (const float*)d_in[12];
  const float* C_im   = (const float*)d_in[13];
  const float* D_skip = (const float*)d_in[14];

  // ---- d_out (67.1 MB f32) doubles as scratch for xn + 2 bf16 weights (dead before final GEMM) ----
  char* ob = (char*)d_out;
  u16* xn    = (u16*)(ob);                         // 33,554,432 B
  u16* Wv_b  = (u16*)(ob + 33554432ull);           //  2,097,152 B
  u16* Wu_b  = (u16*)(ob + 35651584ull);           //    131,072 B

  // ---- workspace layout (aliased by lifetime), total ~224 MiB ----
  char* ws = (char*)d_ws;
  const size_t R1      = 134217728ull;             // after v: u -> (Rcat | WT)
  const size_t OFF_UN  = R1 + 33554432ull;
  const size_t OFF_UNT = OFF_UN + 8388608ull;      // unT, later y
  const size_t OFF_R2  = OFF_UNT + 8388608ull;     // S -> (Ycross | Yloc)
  const size_t OFF_TAB = OFF_R2 + 33554432ull;

  u16*  v     = (u16*)(ws + 0);                    // [32768,2048] bf16
  u16*  u     = (u16*)(ws + R1);
  u16*  Rcat  = (u16*)(ws + R1);                   // 16.8 MB
  u16*  WT    = (u16*)(ws + R1 + 16777216ull);     // 16.8 MB
  u16*  un    = (u16*)(ws + OFF_UN);
  u16*  unT   = (u16*)(ws + OFF_UNT);
  u16*  y     = (u16*)(ws + OFF_UNT);
  float* S    = (float*)(ws + OFF_R2);
  float* Ycross = (float*)(ws + OFF_R2);
  float* Yloc = (float*)(ws + OFF_R2 + 16777216ull);
  char* tp = ws + OFF_TAB;
  u16*  ZC   = (u16*)tp;            tp += 1048576;
  u16*  PC   = (u16*)tp;            tp += 1048576;
  u16*  VC   = (u16*)tp;            tp += 1048576;
  u16*  ccat = (u16*)tp;            tp += 262144;
  float* cre = (float*)tp;          tp += 262144;
  float* cim = (float*)tp;          tp += 262144;
  float* zT  = (float*)tp;          tp += 4096;
  float* kern= (float*)tp;          tp += 262144;
  u16*  Wo_b = (u16*)tp;            tp += 2097152;
  u16*  Wuc_b= (u16*)tp;            tp += 524288;

  // weight conversions (f32 -> bf16), one launch
  k_cvt4<<<9472, 256, 0, stream>>>(W_v, Wv_b, 2048 * 512,
                                   W_u, Wu_b, 128 * 512,
                                   W_uc, Wuc_b, 2048 * 128,
                                   W_o, Wo_b, 512 * 2048);

  k_ln1<<<BL, 256, 0, stream>>>(x, norm_g, norm_b, xn);
  k_prep<<<512, 512, 0, stream>>>(lam_re, lam_im, C_re, C_im, ZC, PC, VC, ccat, cre, cim, zT);

  // v = gelu(xn @ W_v^T)   [32768,2048] bf16 -- 256x256 8-phase
  k_gemm256<1><<<dim3(8, 128), 512, 131072, stream>>>(xn, 512, Wv_b, 512, v, 2048, 512, nullptr, nullptr, nullptr);
  // u = gelu(xn @ W_u^T)   [32768,128] bf16 (N=128 -> old template)
  k_gemm<1><<<dim3(1, 256, 1), 256, 0, stream>>>(xn, 512, 0, Wu_b, 512, 0, u, 128, 0, 512, 128, nullptr, nullptr, nullptr);
  k_ln2<<<BL / 4, 256, 0, stream>>>(u, dss_g, dss_b, un);
  k_transpose<<<512, 256, 0, stream>>>(un, unT);

  // kern[d,h] = Re(c_h . z^d) : A=VC [512,1024], B=ccat [128,1024] -> f32 [512,128]
  k_gemm<0><<<dim3(1, 4, 1), 256, 0, stream>>>(VC, 1024, 0, ccat, 1024, 0, kern, 128, 0, 1024, 128, nullptr, nullptr, nullptr);
  k_rcat<<<16384, 512, 0, stream>>>(kern, Rcat);

  // chunk states: S[m,n'] = sum_i unT[m,i]*ZC[n',i]  [8192,1024] f32
  k_gemm<0><<<dim3(8, 64, 1), 256, 0, stream>>>(unT, 512, 0, ZC, 512, 0, S, 1024, 0, 512, 1024, nullptr, nullptr, nullptr);
  k_scan<<<1024, 256, 0, stream>>>(S, cre, cim, zT, WT);
  // injection: Ycross[i,m] = sum_n' PC[i,n']*WT[m,n']  [512,8192] f32
  k_gemm<0><<<dim3(64, 4, 1), 256, 0, stream>>>(PC, 1024, 0, WT, 1024, 0, Ycross, 8192, 0, 1024, 8192, nullptr, nullptr, nullptr);
  // local conv via block-Toeplitz, single launch (TRI mode: by = i_blk)
  k_gemm<0, true><<<dim3(1, 4, 128), 256, 0, stream>>>(
      Rcat, 512, 65536, unT, 65536, 512, Yloc, 64, 32768, 512, 64, nullptr, nullptr, nullptr);
  k_assemble<<<16384, 256, 0, stream>>>(Yloc, Ycross, un, D_skip, y);

  // uc = y @ W_uc^T, fused t = uc*v (in place over v) -- 256x256 8-phase
  k_gemm256<2><<<dim3(8, 128), 512, 131072, stream>>>(y, 128, Wuc_b, 128, v, 2048, 128, v, nullptr, nullptr);
  // out = t @ W_o^T + b_o + x   (f32 out) -- 256x256 8-phase
  k_gemm256<0><<<dim3(2, 128), 512, 131072, stream>>>(v, 2048, Wo_b, 2048, d_out, 512, 2048, nullptr, x, b_o);
}